// Round 13
// baseline (138.180 us; speedup 1.0000x reference)
//
#include <hip/hip_runtime.h>
#include <hip/hip_bf16.h>

typedef unsigned short u16;
typedef unsigned int   u32;
typedef unsigned long long u64;
typedef __attribute__((ext_vector_type(8))) short short8;   // 8 bf16 (4 VGPRs)
typedef __attribute__((ext_vector_type(4))) float float4v;  // 4 fp32 acc

#define N 8192
#define D 128
#define C 1000
#define TILE 128
#define NW64 (N / 64)   // 128 packed words per class row
#define NT   (N / TILE) // 64 tiles per axis
#define JQ 2            // j-tiles per block (strip chunk)
#define JW (JQ * 2)     // Ms1 words per row per block
#define NBLKS 1056      // sum_{it} ceil((64-it)/2)
#define LOG2E 1.44269504088896340736f

// ---------------------------------------------------------------------------
// Kernel 1 (prep): fused pack + norm. (R18 version, byte-identical.)
// ---------------------------------------------------------------------------
__global__ void prep_kernel(const float* __restrict__ nm, u64* __restrict__ packed,
                            const float* __restrict__ x, const float* __restrict__ pr,
                            u16* __restrict__ xnb, float* __restrict__ p_out,
                            float* __restrict__ den, float* __restrict__ num,
                            const float* __restrict__ tp, const float* __restrict__ mp) {
    __shared__ u32 Ls[64 * 65];
    const int bid  = blockIdx.x;
    const int lane = threadIdx.x & 63;
    const int wv   = threadIdx.x >> 6;

    if (bid < 2048) {
        // ---- pack part: 64x64 tile through LDS, column ballots ----
        const int jt = bid & 127;
        const int lt = bid >> 7;
        const int j0 = jt * 64;
        const int l0 = lt * 64;

        if (lt < 15) {
            const int tid = threadIdx.x;
            #pragma unroll
            for (int it = 0; it < 4; it++) {
                const int r  = it * 16 + (tid >> 4);
                const int c0 = (tid & 15) * 4;
                const float4 v = *(const float4*)(nm + (size_t)(j0 + r) * C + l0 + c0);
                Ls[r * 65 + c0 + 0] = (v.x > 0.5f) ? 1u : 0u;
                Ls[r * 65 + c0 + 1] = (v.y > 0.5f) ? 1u : 0u;
                Ls[r * 65 + c0 + 2] = (v.z > 0.5f) ? 1u : 0u;
                Ls[r * 65 + c0 + 3] = (v.w > 0.5f) ? 1u : 0u;
            }
        } else {
            const int l  = l0 + lane;
            const bool lv = l < C;
            #pragma unroll
            for (int rr = 0; rr < 16; rr++) {
                const int r = wv * 16 + rr;
                float v = lv ? nm[(size_t)(j0 + r) * C + l] : 0.0f;
                Ls[r * 65 + lane] = (v > 0.5f) ? 1u : 0u;
            }
        }
        __syncthreads();
        #pragma unroll
        for (int cc = 0; cc < 16; cc++) {
            const int c = wv * 16 + cc;
            u64 m = __ballot(Ls[lane * 65 + c] != 0u);
            if (lane == 0 && (lt * 64 + c) < C)
                packed[(size_t)(lt * 64 + c) * NW64 + jt] = m;
        }
    } else {
        // ---- norm part: one wave per row ----
        const int row = (bid - 2048) * 4 + wv;
        const float2* xr  = (const float2*)(x  + (size_t)row * D);
        const float2* prr = (const float2*)(pr + (size_t)row * D);
        float2 xv = xr[lane];
        float2 pv = prr[lane];

        float sx  = xv.x * xv.x + xv.y * xv.y;
        float sp  = pv.x * pv.x + pv.y * pv.y;
        float sxp = xv.x * pv.x + xv.y * pv.y;
        #pragma unroll
        for (int off = 32; off; off >>= 1) {
            sx  += __shfl_xor(sx,  off);
            sp  += __shfl_xor(sp,  off);
            sxp += __shfl_xor(sxp, off);
        }
        float nx = fmaxf(sqrtf(sx), 1e-8f);
        float np = fmaxf(sqrtf(sp), 1e-8f);
        float inv = 1.0f / nx;

        __hip_bfloat16 b0 = __float2bfloat16(xv.x * inv);
        __hip_bfloat16 b1 = __float2bfloat16(xv.y * inv);
        ((__hip_bfloat162*)xnb)[(size_t)row * 64 + lane] = __halves2bfloat162(b0, b1);

        if (lane == 0) {
            float T = tp[0], M = mp[0];
            p_out[row] = __expf((sxp / (nx * np) - M) / T);
            den[row] = 0.0f;
            num[row] = 0.0f;
        }
    }
}

// ---------------------------------------------------------------------------
// Kernel 2 (cc_main): R24 — SYMMETRY: compute only tile pairs (it <= jt).
// sim is symmetric: off-diagonal tile (it,jt) is computed ONCE; its e-values
// feed row-sums for the i-range (as before) AND column-sums for the j-range
// (den[j] += e; num[j] += mask[label_j][i]*e via a second 2KB mask stage Ms2).
// Tile-stages drop 4096 -> 2080 (0.51x) — this halves MFMA, exp2, LDS reads,
// B staging AND the per-tile drain overhead that defeated all schedule fixes
// (R17/R19/R21). The per-tile inner cadence is byte-identical to the defended
// R18 structure: full 32KB stage, ONE drain per tile, reg-A, XOR-swizzled B.
// Geometry: JQ=2 strips -> 1056 blocks (load-balanced backfill);
// LDS 32768+4096+2048 = 38912 B -> 4 blocks/CU. lb(256,2) (R4: load-bearing).
// Diagonal tiles (jt==it): row-accumulate only, DIAG zeroing (complete,
// since the full 128x128 tile contains both (i,j) and (j,i)).
// ---------------------------------------------------------------------------
#define AS1 __attribute__((address_space(1)))
#define AS3 __attribute__((address_space(3)))

static __device__ __forceinline__ void load_lds16(const u16* g, u16* l) {
    __builtin_amdgcn_global_load_lds((const AS1 u32*)(const void*)g,
                                     (AS3 u32*)(void*)l, 16, 0, 0);
}

template <bool RELOAD>
__device__ __forceinline__ void mfma_chunk(float4v (&acc)[2][2], const short8 (&a_f)[4][2],
                                           short8 (&bc)[4][2], const u16* Bnext,
                                           const int (&koff)[4]) {
    #pragma unroll
    for (int a = 0; a < 2; a++)
        #pragma unroll
        for (int b = 0; b < 2; b++)
            acc[a][b] = (float4v){0.f, 0.f, 0.f, 0.f};
    #pragma unroll
    for (int kk = 0; kk < 4; kk++) {
        #pragma unroll
        for (int tm = 0; tm < 2; tm++)
            #pragma unroll
            for (int tn = 0; tn < 2; tn++)
                acc[tm][tn] = __builtin_amdgcn_mfma_f32_16x16x32_bf16(
                    a_f[kk][tm], bc[kk][tn], acc[tm][tn], 0, 0, 0);
        if (RELOAD) {
            #pragma unroll
            for (int tn = 0; tn < 2; tn++)
                bc[kk][tn] = *(const short8*)(Bnext + tn * 2048 + koff[kk]);
        }
    }
}

// CI = chunk index (0..3): local j = CI*32 + tn*16 + m0.
// DIAG tile: row-path only, zero the diagonal. Off-diag: row-path + col-path.
// Ms1 bit for (i,j): packed[label_i] bit j  -> word lrow*JW + q*2 + (CI>>1),
//   bit m0 + ((CI&1)*2+tn)*16.
// Ms2 bit for (j,i): packed[label_j] bit i  -> Ms2[jrow][wv>>1],
//   bit (wv&1)*32 + tm*16 + kq*4 + r.
template <bool DIAG, int CI>
__device__ __forceinline__ void epi_chunk(const float4v (&acc)[2][2],
                                          const u64* __restrict__ Ms,
                                          const u64* __restrict__ Ms2,
                                          float (&dacc)[2][4], float (&nacc)[2][4],
                                          float* __restrict__ den, float* __restrict__ num,
                                          int wv, int kq, int m0,
                                          int ibase, int jbase, int q,
                                          float kA2, float kB2) {
    float cd[2] = {0.0f, 0.0f};
    float cn[2] = {0.0f, 0.0f};
    u64 w2[2] = {0, 0};
    if (!DIAG) {
        #pragma unroll
        for (int tn = 0; tn < 2; tn++)
            w2[tn] = Ms2[(CI * 32 + tn * 16 + m0) * 2 + (wv >> 1)];
    }
    const int base2 = (wv & 1) * 32 + kq * 4;
    #pragma unroll
    for (int tm = 0; tm < 2; tm++) {
        #pragma unroll
        for (int r = 0; r < 4; r++) {
            const int lrow = wv * 32 + tm * 16 + kq * 4 + r;
            const u64 ws = Ms[lrow * JW + q * 2 + (CI >> 1)] >> m0;
            const int gi = ibase + lrow;
            #pragma unroll
            for (int tn = 0; tn < 2; tn++) {
                float e = __builtin_amdgcn_exp2f(fmaf(acc[tm][tn][r], kA2, kB2));
                if (DIAG) {
                    const int gj = jbase + CI * 32 + tn * 16 + m0;
                    if (gi == gj) e = 0.0f;
                }
                dacc[tm][r] += e;
                const u32 bit = (u32)(ws >> (((CI & 1) * 2 + tn) * 16)) & 1u;
                nacc[tm][r] = fmaf((float)bit, e, nacc[tm][r]);
                if (!DIAG) {
                    cd[tn] += e;
                    const u32 b2 = (u32)(w2[tn] >> (base2 + tm * 16 + r)) & 1u;
                    cn[tn] = fmaf((float)b2, e, cn[tn]);
                }
            }
        }
    }
    if (!DIAG) {
        // reduce col-sums over the 4 kq groups, then per-wave atomics
        #pragma unroll
        for (int tn = 0; tn < 2; tn++) {
            float d = cd[tn], n = cn[tn];
            d += __shfl_xor(d, 16); d += __shfl_xor(d, 32);
            n += __shfl_xor(n, 16); n += __shfl_xor(n, 32);
            if (kq == 0) {
                const int gj = jbase + CI * 32 + tn * 16 + m0;
                atomicAdd(&den[gj], d);
                atomicAdd(&num[gj], n);
            }
        }
    }
}

__global__ __launch_bounds__(256, 2)
void cc_main(const u16* __restrict__ xnb, const int* __restrict__ labels,
             const u64* __restrict__ packed,
             float* __restrict__ den, float* __restrict__ num,
             const float* __restrict__ tp, const float* __restrict__ mp) {
    __shared__ u16 Bs[TILE * D];      // 32768 B, linear (swizzle in addresses)
    __shared__ u64 Ms[TILE * JW];     // 4096 B, [row][4] for this strip chunk
    __shared__ u64 Ms2[TILE * 2];     // 2048 B, [jrow][2] for the i-tile cols
                                      // total 38912 B -> 4 blocks/CU

    const int tid  = threadIdx.x;
    const int lane = tid & 63;
    const int wv   = tid >> 6;        // wave = 32 rows x 128 cols
    const int m0   = lane & 15;
    const int kq   = lane >> 4;

    // --- upper-triangle strip mapping: block -> (it, jt0) ---
    {
    }
    int brem = blockIdx.x;
    int it = 0;
    int nb = 32;                      // ceil(64/2)
    while (brem >= nb) { brem -= nb; it++; nb = (NT - it + 1) >> 1; }
    const int jt0  = it + brem * 2;
    const int jcnt = (NT - jt0 < 2) ? (NT - jt0) : 2;
    const int ibase = it * TILE;

    const float T = tp[0];
    const float M = mp[0];
    const float kA2 = LOG2E / T;
    const float kB2 = -M * LOG2E / T;

    // stage Ms1: 128 rows x 4 words (clamped at the triangle edge)
    #pragma unroll
    for (int t = 0; t < 2; t++) {
        const int idx = t * 256 + tid;
        const int row = idx >> 2, h = idx & 3;
        int wd = jt0 * 2 + h; if (wd > NW64 - 1) wd = NW64 - 1;
        const int lab = labels[ibase + row];
        Ms[idx] = packed[(size_t)lab * NW64 + wd];
    }

    // A fragments: 32 rows/wave, loop-invariant, register-resident (32 VGPR).
    const u16* Alane = xnb + (size_t)(ibase + wv * 32 + m0) * D + kq * 8;
    short8 a_f[4][2];
    #pragma unroll
    for (int kk = 0; kk < 4; kk++)
        #pragma unroll
        for (int tm = 0; tm < 2; tm++)
            a_f[kk][tm] = *(const short8*)(Alane + tm * (16 * D) + kk * 32);

    // --- staging geometry (global source pre-swizzled; LDS linear) ---
    const int srow  = wv * 4 + (lane >> 4);               // row base within 16-row group
    const int sunit = (lane & 15) ^ (srow & 7);           // swizzled source unit
    const u16* Bsrc = xnb + (size_t)srow * D + sunit * 8; // + jbase*D + rnd*16*D
    u16* BsDst = (u16*)Bs + wv * 512;                     // wave-uniform; + rnd*2048

    // --- read geometry ---
    const int swz7 = m0 & 7;
    int koff[4];
    #pragma unroll
    for (int kk = 0; kk < 4; kk++) koff[kk] = ((kq + kk * 4) ^ swz7) * 8;
    const u16* LBrd = (const u16*)Bs + m0 * 128;          // + c*4096 + tn*2048 + koff

    float dacc[2][4] = {};
    float nacc[2][4] = {};
    float4v acc[2][2];
    short8 bc[4][2];

    for (int q = 0; q < jcnt; q++) {
        const int jt = jt0 + q;
        const int jbase = jt * TILE;
        const bool diag = (jt == it);

        __syncthreads();                 // Bs/Ms2 free (q=0: also orders Ms writes)
        {   // stage B tile jt: 8 rounds x (256 thr x 16B) = 32 KB
            const u16* sq = Bsrc + (size_t)jbase * D;
            #pragma unroll
            for (int rnd = 0; rnd < 8; rnd++)
                load_lds16(sq + rnd * 16 * D, BsDst + rnd * 2048);
        }
        {   // stage Ms2: mask[label_j][i-tile words] (128 rows x 2 words)
            const int jrow = jbase + (tid >> 1);
            Ms2[tid] = packed[(size_t)labels[jrow] * NW64 + it * 2 + (tid & 1)];
        }
        __syncthreads();                 // staging complete (barrier drains vmcnt)

        // chunk 0 fragments
        #pragma unroll
        for (int kk = 0; kk < 4; kk++)
            #pragma unroll
            for (int tn = 0; tn < 2; tn++)
                bc[kk][tn] = *(const short8*)(LBrd + tn * 2048 + koff[kk]);

        mfma_chunk<true>(acc, a_f, bc, LBrd + 1 * 4096, koff);
        if (diag) epi_chunk<true , 0>(acc, Ms, Ms2, dacc, nacc, den, num, wv, kq, m0, ibase, jbase, q, kA2, kB2);
        else      epi_chunk<false, 0>(acc, Ms, Ms2, dacc, nacc, den, num, wv, kq, m0, ibase, jbase, q, kA2, kB2);

        mfma_chunk<true>(acc, a_f, bc, LBrd + 2 * 4096, koff);
        if (diag) epi_chunk<true , 1>(acc, Ms, Ms2, dacc, nacc, den, num, wv, kq, m0, ibase, jbase, q, kA2, kB2);
        else      epi_chunk<false, 1>(acc, Ms, Ms2, dacc, nacc, den, num, wv, kq, m0, ibase, jbase, q, kA2, kB2);

        mfma_chunk<true>(acc, a_f, bc, LBrd + 3 * 4096, koff);
        if (diag) epi_chunk<true , 2>(acc, Ms, Ms2, dacc, nacc, den, num, wv, kq, m0, ibase, jbase, q, kA2, kB2);
        else      epi_chunk<false, 2>(acc, Ms, Ms2, dacc, nacc, den, num, wv, kq, m0, ibase, jbase, q, kA2, kB2);

        mfma_chunk<false>(acc, a_f, bc, LBrd, koff);
        if (diag) epi_chunk<true , 3>(acc, Ms, Ms2, dacc, nacc, den, num, wv, kq, m0, ibase, jbase, q, kA2, kB2);
        else      epi_chunk<false, 3>(acc, Ms, Ms2, dacc, nacc, den, num, wv, kq, m0, ibase, jbase, q, kA2, kB2);
    }

    // row-path: reduce across the 16 column-lanes, then atomics
    #pragma unroll
    for (int tm = 0; tm < 2; tm++) {
        #pragma unroll
        for (int r = 0; r < 4; r++) {
            float d = dacc[tm][r], n = nacc[tm][r];
            #pragma unroll
            for (int off = 1; off < 16; off <<= 1) {
                d += __shfl_xor(d, off);
                n += __shfl_xor(n, off);
            }
            if (m0 == 0) {
                const int gi = ibase + wv * 32 + tm * 16 + kq * 4 + r;
                atomicAdd(&den[gi], d);
                atomicAdd(&num[gi], n);
            }
        }
    }
}

// ---------------------------------------------------------------------------
// Kernel 3: final loss = mean_i -log(T * (p_i + num_i) / (p_i + den_i))
// float4-vectorized (R22).
// ---------------------------------------------------------------------------
__global__ void loss_kernel(const float* __restrict__ p, const float* __restrict__ den,
                            const float* __restrict__ num, float* __restrict__ out,
                            const float* __restrict__ tp) {
    __shared__ float red[16];
    const float T = tp[0];
    float s = 0.0f;
    #pragma unroll
    for (int t = 0; t < N / 4096; t++) {
        const int i = t * 1024 + threadIdx.x;
        const float4 pi = *(const float4*)(p   + i * 4);
        const float4 dn = *(const float4*)(den + i * 4);
        const float4 nu = *(const float4*)(num + i * 4);
        s += -__logf(T * (pi.x + nu.x) / (pi.x + dn.x));
        s += -__logf(T * (pi.y + nu.y) / (pi.y + dn.y));
        s += -__logf(T * (pi.z + nu.z) / (pi.z + dn.z));
        s += -__logf(T * (pi.w + nu.w) / (pi.w + dn.w));
    }
    #pragma unroll
    for (int off = 32; off; off >>= 1) s += __shfl_xor(s, off);
    const int lane = threadIdx.x & 63, wv = threadIdx.x >> 6;
    if (lane == 0) red[wv] = s;
    __syncthreads();
    if (wv == 0) {
        float t = (lane < 16) ? red[lane] : 0.0f;
        #pragma unroll
        for (int off = 8; off; off >>= 1) t += __shfl_xor(t, off);
        if (lane == 0) out[0] = t / (float)N;
    }
}

// ---------------------------------------------------------------------------
extern "C" void kernel_launch(void* const* d_in, const int* in_sizes, int n_in,
                              void* d_out, int out_size, void* d_ws, size_t ws_size,
                              hipStream_t stream) {
    (void)in_sizes; (void)n_in; (void)out_size; (void)ws_size;
    const float* inst   = (const float*)d_in[0];
    const float* proxy  = (const float*)d_in[1];
    const float* nm     = (const float*)d_in[2];
    const int*   labels = (const int*)d_in[3];
    const float* temp   = (const float*)d_in[4];
    const float* marg   = (const float*)d_in[5];
    float* out = (float*)d_out;

    char* ws = (char*)d_ws;
    u16*   xnb    = (u16*)ws;                         // N*D*2      = 2,097,152 B
    float* p_arr  = (float*)(ws + 2097152);           // N*4        = 32,768 B
    u64*   packed = (u64*)(ws + 2129920);             // C*128*8    = 1,024,000 B
    float* den    = (float*)(ws + 3153920);           // N*4
    float* num    = (float*)(ws + 3186688);           // N*4

    prep_kernel<<<4096, 256, 0, stream>>>(nm, packed, inst, proxy, xnb, p_arr,
                                          den, num, temp, marg);
    cc_main<<<NBLKS, 256, 0, stream>>>(xnb, labels, packed, den, num, temp, marg);
    loss_kernel<<<1, 1024, 0, stream>>>(p_arr, den, num, out, temp);
}

// Round 14
// 125.673 us; speedup vs baseline: 1.0995x; 1.0995x over previous
//
#include <hip/hip_runtime.h>
#include <hip/hip_bf16.h>

typedef unsigned short u16;
typedef unsigned int   u32;
typedef unsigned long long u64;
typedef __attribute__((ext_vector_type(8))) short short8;   // 8 bf16 (4 VGPRs)
typedef __attribute__((ext_vector_type(4))) float float4v;  // 4 fp32 acc

#define N 8192
#define D 128
#define C 1000
#define TILE 128
#define NW64 (N / 64)  // 128 packed words per class row
#define JQ 4           // j-tiles per block
#define GRIDY 16       // j-splits; GRIDY*JQ = 64 tiles
#define JW (JQ * 2)    // mask words per row per block
#define LOG2E 1.44269504088896340736f

// ---------------------------------------------------------------------------
// Kernel 1 (prep): fused pack + norm. (R18 version, byte-identical.)
// ---------------------------------------------------------------------------
__global__ void prep_kernel(const float* __restrict__ nm, u64* __restrict__ packed,
                            const float* __restrict__ x, const float* __restrict__ pr,
                            u16* __restrict__ xnb, float* __restrict__ p_out,
                            float* __restrict__ den, float* __restrict__ num,
                            const float* __restrict__ tp, const float* __restrict__ mp) {
    __shared__ u32 Ls[64 * 65];
    const int bid  = blockIdx.x;
    const int lane = threadIdx.x & 63;
    const int wv   = threadIdx.x >> 6;

    if (bid < 2048) {
        // ---- pack part: 64x64 tile through LDS, column ballots ----
        const int jt = bid & 127;
        const int lt = bid >> 7;
        const int j0 = jt * 64;
        const int l0 = lt * 64;

        if (lt < 15) {
            const int tid = threadIdx.x;
            #pragma unroll
            for (int it = 0; it < 4; it++) {
                const int r  = it * 16 + (tid >> 4);
                const int c0 = (tid & 15) * 4;
                const float4 v = *(const float4*)(nm + (size_t)(j0 + r) * C + l0 + c0);
                Ls[r * 65 + c0 + 0] = (v.x > 0.5f) ? 1u : 0u;
                Ls[r * 65 + c0 + 1] = (v.y > 0.5f) ? 1u : 0u;
                Ls[r * 65 + c0 + 2] = (v.z > 0.5f) ? 1u : 0u;
                Ls[r * 65 + c0 + 3] = (v.w > 0.5f) ? 1u : 0u;
            }
        } else {
            const int l  = l0 + lane;
            const bool lv = l < C;
            #pragma unroll
            for (int rr = 0; rr < 16; rr++) {
                const int r = wv * 16 + rr;
                float v = lv ? nm[(size_t)(j0 + r) * C + l] : 0.0f;
                Ls[r * 65 + lane] = (v > 0.5f) ? 1u : 0u;
            }
        }
        __syncthreads();
        #pragma unroll
        for (int cc = 0; cc < 16; cc++) {
            const int c = wv * 16 + cc;
            u64 m = __ballot(Ls[lane * 65 + c] != 0u);
            if (lane == 0 && (lt * 64 + c) < C)
                packed[(size_t)(lt * 64 + c) * NW64 + jt] = m;
        }
    } else {
        // ---- norm part: one wave per row ----
        const int row = (bid - 2048) * 4 + wv;
        const float2* xr  = (const float2*)(x  + (size_t)row * D);
        const float2* prr = (const float2*)(pr + (size_t)row * D);
        float2 xv = xr[lane];
        float2 pv = prr[lane];

        float sx  = xv.x * xv.x + xv.y * xv.y;
        float sp  = pv.x * pv.x + pv.y * pv.y;
        float sxp = xv.x * pv.x + xv.y * pv.y;
        #pragma unroll
        for (int off = 32; off; off >>= 1) {
            sx  += __shfl_xor(sx,  off);
            sp  += __shfl_xor(sp,  off);
            sxp += __shfl_xor(sxp, off);
        }
        float nx = fmaxf(sqrtf(sx), 1e-8f);
        float np = fmaxf(sqrtf(sp), 1e-8f);
        float inv = 1.0f / nx;

        __hip_bfloat16 b0 = __float2bfloat16(xv.x * inv);
        __hip_bfloat16 b1 = __float2bfloat16(xv.y * inv);
        ((__hip_bfloat162*)xnb)[(size_t)row * 64 + lane] = __halves2bfloat162(b0, b1);

        if (lane == 0) {
            float T = tp[0], M = mp[0];
            p_out[row] = __expf((sxp / (nx * np) - M) / T);
            den[row] = 0.0f;
            num[row] = 0.0f;
        }
    }
}

// ---------------------------------------------------------------------------
// Kernel 2 (cc_main): R25 — restore the measured optimum (R18/R22 body,
// three independent confirmations at 125.3/126.5/126.9 us total).
// Defended structure (seven failed alternatives adjudicated):
//  - full 32KB B-tile stage per q via global_load_lds w=16, ONE drain per q
//    (R17 ping-pong +79us; R19 half-tile cadence +7.5us);
//  - Ms per-row [128][8] (R20 transpose +3.8us: staging gathers outweigh the
//    broadcast-read "conflict"); no Ms register hoist (R23: neutral, hidden
//    under drains);
//  - NO end-of-kernel fence/atomic tail (R21: +79us, occupancy halved);
//  - full-square grid, no symmetry (R24: 0.51x work but +11us — epilogue
//    growth + contended column atomics + halved prologue amortization);
//  - lb(256,2) (R4: arg=4 halves the VGPR cap -> 115MB scratch spill);
//  - reg-A (32 VGPR) + B-through-LDS with XOR swizzle on the global source
//    and read address (R15/R16: the B-instruction-count fix).
// ---------------------------------------------------------------------------
#define AS1 __attribute__((address_space(1)))
#define AS3 __attribute__((address_space(3)))

static __device__ __forceinline__ void load_lds16(const u16* g, u16* l) {
    __builtin_amdgcn_global_load_lds((const AS1 u32*)(const void*)g,
                                     (AS3 u32*)(void*)l, 16, 0, 0);
}

template <bool RELOAD>
__device__ __forceinline__ void mfma_chunk(float4v (&acc)[2][2], const short8 (&a_f)[4][2],
                                           short8 (&bc)[4][2], const u16* Bnext,
                                           const int (&koff)[4]) {
    #pragma unroll
    for (int a = 0; a < 2; a++)
        #pragma unroll
        for (int b = 0; b < 2; b++)
            acc[a][b] = (float4v){0.f, 0.f, 0.f, 0.f};
    #pragma unroll
    for (int kk = 0; kk < 4; kk++) {
        #pragma unroll
        for (int tm = 0; tm < 2; tm++)
            #pragma unroll
            for (int tn = 0; tn < 2; tn++)
                acc[tm][tn] = __builtin_amdgcn_mfma_f32_16x16x32_bf16(
                    a_f[kk][tm], bc[kk][tn], acc[tm][tn], 0, 0, 0);
        if (RELOAD) {
            #pragma unroll
            for (int tn = 0; tn < 2; tn++)
                bc[kk][tn] = *(const short8*)(Bnext + tn * 2048 + koff[kk]);
        }
    }
}

// CI = compile-time chunk index (0..3): local j = CI*32 + tn*16 + m0.
template <bool DIAG, int CI>
__device__ __forceinline__ void epi_chunk(const float4v (&acc)[2][2], const u64* __restrict__ Ms,
                                          float (&dacc)[2][4], float (&nacc)[2][4],
                                          int wv, int kq, int m0,
                                          int ibase, int jbase, int q,
                                          float kA2, float kB2) {
    #pragma unroll
    for (int tm = 0; tm < 2; tm++) {
        #pragma unroll
        for (int r = 0; r < 4; r++) {
            const int lrow = wv * 32 + tm * 16 + kq * 4 + r;
            const u64 ws = Ms[lrow * JW + q * 2 + (CI >> 1)] >> m0;
            const int gi = ibase + lrow;
            #pragma unroll
            for (int tn = 0; tn < 2; tn++) {
                float e = __builtin_amdgcn_exp2f(fmaf(acc[tm][tn][r], kA2, kB2));
                if (DIAG) {
                    const int gj = jbase + CI * 32 + tn * 16 + m0;
                    if (gi == gj) e = 0.0f;
                }
                dacc[tm][r] += e;
                const u32 bit = (u32)(ws >> (((CI & 1) * 2 + tn) * 16)) & 1u;
                nacc[tm][r] = fmaf((float)bit, e, nacc[tm][r]);
            }
        }
    }
}

__global__ __launch_bounds__(256, 2)
void cc_main(const u16* __restrict__ xnb, const int* __restrict__ labels,
             const u64* __restrict__ packed,
             float* __restrict__ den, float* __restrict__ num,
             const float* __restrict__ tp, const float* __restrict__ mp) {
    __shared__ u16 Bs[TILE * D];      // 32768 B, linear (swizzle in addresses)
    __shared__ u64 Ms[TILE * JW];     // 8192 B -> total 40960 B, exactly 4 blk/CU

    const int tid  = threadIdx.x;
    const int lane = tid & 63;
    const int wv   = tid >> 6;        // wave = 32 rows x 128 cols
    const int m0   = lane & 15;
    const int kq   = lane >> 4;
    const int ibase  = blockIdx.x * TILE;
    const int jsplit = blockIdx.y;
    const int jt0    = jsplit * JQ;

    const float T = tp[0];
    const float M = mp[0];
    const float kA2 = LOG2E / T;
    const float kB2 = -M * LOG2E / T;

    // stage mask words: 128 rows x 8 words for this j-split
    #pragma unroll
    for (int t = 0; t < 4; t++) {
        const int idx = t * 256 + tid;
        const int row = idx >> 3, h = idx & 7;
        const int lab = labels[ibase + row];
        Ms[idx] = packed[(size_t)lab * NW64 + jt0 * 2 + h];
    }

    // A fragments: 32 rows/wave, loop-invariant, register-resident (32 VGPR).
    const u16* Alane = xnb + (size_t)(ibase + wv * 32 + m0) * D + kq * 8;
    short8 a_f[4][2];
    #pragma unroll
    for (int kk = 0; kk < 4; kk++)
        #pragma unroll
        for (int tm = 0; tm < 2; tm++)
            a_f[kk][tm] = *(const short8*)(Alane + tm * (16 * D) + kk * 32);

    // --- staging geometry (global source pre-swizzled; LDS linear) ---
    // LDS unit (row, u) holds global unit (row, u ^ (row&7)).
    const int srow  = wv * 4 + (lane >> 4);               // row base within 16-row group
    const int sunit = (lane & 15) ^ (srow & 7);           // swizzled source unit
    const u16* Bsrc = xnb + (size_t)srow * D + sunit * 8; // + jbase*D + rnd*16*D
    u16* BsDst = (u16*)Bs + wv * 512;                     // wave-uniform; + rnd*2048

    // --- read geometry ---
    const int swz7 = m0 & 7;
    int koff[4];
    #pragma unroll
    for (int kk = 0; kk < 4; kk++) koff[kk] = ((kq + kk * 4) ^ swz7) * 8;
    const u16* LBrd = (const u16*)Bs + m0 * 128;          // + c*4096 + tn*2048 + koff

    float dacc[2][4] = {};
    float nacc[2][4] = {};
    float4v acc[2][2];
    short8 bc[4][2];

    for (int q = 0; q < JQ; q++) {
        const int jt = jt0 + q;
        const int jbase = jt * TILE;
        const bool diag = (jt == blockIdx.x);

        __syncthreads();                 // Bs free (q=0: also orders Ms writes)
        {   // stage B tile jt: 8 rounds x (256 thr x 16B) = 32 KB
            const u16* sq = Bsrc + (size_t)jbase * D;
            #pragma unroll
            for (int rnd = 0; rnd < 8; rnd++)
                load_lds16(sq + rnd * 16 * D, BsDst + rnd * 2048);
        }
        __syncthreads();                 // staging complete (barrier drains vmcnt)

        // chunk 0 fragments
        #pragma unroll
        for (int kk = 0; kk < 4; kk++)
            #pragma unroll
            for (int tn = 0; tn < 2; tn++)
                bc[kk][tn] = *(const short8*)(LBrd + tn * 2048 + koff[kk]);

        mfma_chunk<true>(acc, a_f, bc, LBrd + 1 * 4096, koff);
        if (diag) epi_chunk<true , 0>(acc, Ms, dacc, nacc, wv, kq, m0, ibase, jbase, q, kA2, kB2);
        else      epi_chunk<false, 0>(acc, Ms, dacc, nacc, wv, kq, m0, ibase, jbase, q, kA2, kB2);

        mfma_chunk<true>(acc, a_f, bc, LBrd + 2 * 4096, koff);
        if (diag) epi_chunk<true , 1>(acc, Ms, dacc, nacc, wv, kq, m0, ibase, jbase, q, kA2, kB2);
        else      epi_chunk<false, 1>(acc, Ms, dacc, nacc, wv, kq, m0, ibase, jbase, q, kA2, kB2);

        mfma_chunk<true>(acc, a_f, bc, LBrd + 3 * 4096, koff);
        if (diag) epi_chunk<true , 2>(acc, Ms, dacc, nacc, wv, kq, m0, ibase, jbase, q, kA2, kB2);
        else      epi_chunk<false, 2>(acc, Ms, dacc, nacc, wv, kq, m0, ibase, jbase, q, kA2, kB2);

        mfma_chunk<false>(acc, a_f, bc, LBrd, koff);
        if (diag) epi_chunk<true , 3>(acc, Ms, dacc, nacc, wv, kq, m0, ibase, jbase, q, kA2, kB2);
        else      epi_chunk<false, 3>(acc, Ms, dacc, nacc, wv, kq, m0, ibase, jbase, q, kA2, kB2);
    }

    // reduce across the 16 column-lanes, then atomics
    #pragma unroll
    for (int tm = 0; tm < 2; tm++) {
        #pragma unroll
        for (int r = 0; r < 4; r++) {
            float d = dacc[tm][r], n = nacc[tm][r];
            #pragma unroll
            for (int off = 1; off < 16; off <<= 1) {
                d += __shfl_xor(d, off);
                n += __shfl_xor(n, off);
            }
            if (m0 == 0) {
                const int gi = ibase + wv * 32 + tm * 16 + kq * 4 + r;
                atomicAdd(&den[gi], d);
                atomicAdd(&num[gi], n);
            }
        }
    }
}

// ---------------------------------------------------------------------------
// Kernel 3: final loss = mean_i -log(T * (p_i + num_i) / (p_i + den_i))
// float4-vectorized (R22).
// ---------------------------------------------------------------------------
__global__ void loss_kernel(const float* __restrict__ p, const float* __restrict__ den,
                            const float* __restrict__ num, float* __restrict__ out,
                            const float* __restrict__ tp) {
    __shared__ float red[16];
    const float T = tp[0];
    float s = 0.0f;
    #pragma unroll
    for (int t = 0; t < N / 4096; t++) {
        const int i = t * 1024 + threadIdx.x;
        const float4 pi = *(const float4*)(p   + i * 4);
        const float4 dn = *(const float4*)(den + i * 4);
        const float4 nu = *(const float4*)(num + i * 4);
        s += -__logf(T * (pi.x + nu.x) / (pi.x + dn.x));
        s += -__logf(T * (pi.y + nu.y) / (pi.y + dn.y));
        s += -__logf(T * (pi.z + nu.z) / (pi.z + dn.z));
        s += -__logf(T * (pi.w + nu.w) / (pi.w + dn.w));
    }
    #pragma unroll
    for (int off = 32; off; off >>= 1) s += __shfl_xor(s, off);
    const int lane = threadIdx.x & 63, wv = threadIdx.x >> 6;
    if (lane == 0) red[wv] = s;
    __syncthreads();
    if (wv == 0) {
        float t = (lane < 16) ? red[lane] : 0.0f;
        #pragma unroll
        for (int off = 8; off; off >>= 1) t += __shfl_xor(t, off);
        if (lane == 0) out[0] = t / (float)N;
    }
}

// ---------------------------------------------------------------------------
extern "C" void kernel_launch(void* const* d_in, const int* in_sizes, int n_in,
                              void* d_out, int out_size, void* d_ws, size_t ws_size,
                              hipStream_t stream) {
    (void)in_sizes; (void)n_in; (void)out_size; (void)ws_size;
    const float* inst   = (const float*)d_in[0];
    const float* proxy  = (const float*)d_in[1];
    const float* nm     = (const float*)d_in[2];
    const int*   labels = (const int*)d_in[3];
    const float* temp   = (const float*)d_in[4];
    const float* marg   = (const float*)d_in[5];
    float* out = (float*)d_out;

    char* ws = (char*)d_ws;
    u16*   xnb    = (u16*)ws;                         // N*D*2      = 2,097,152 B
    float* p_arr  = (float*)(ws + 2097152);           // N*4        = 32,768 B
    u64*   packed = (u64*)(ws + 2129920);             // C*128*8    = 1,024,000 B
    float* den    = (float*)(ws + 3153920);           // N*4
    float* num    = (float*)(ws + 3186688);           // N*4

    prep_kernel<<<4096, 256, 0, stream>>>(nm, packed, inst, proxy, xnb, p_arr,
                                          den, num, temp, marg);
    cc_main<<<dim3(N / TILE, GRIDY), 256, 0, stream>>>(xnb, labels, packed, den, num, temp, marg);
    loss_kernel<<<1, 1024, 0, stream>>>(p_arr, den, num, out, temp);
}